// Round 5
// baseline (531.859 us; speedup 1.0000x reference)
//
#include <hip/hip_runtime.h>
#include <stdint.h>

typedef unsigned short u16;
typedef __bf16 bf16x8 __attribute__((ext_vector_type(8)));
typedef float f32x4 __attribute__((ext_vector_type(4)));

__device__ __forceinline__ u16 f2bf(float f) {
  union { float f; unsigned u; } v; v.f = f;
  return (u16)((v.u + 0x7FFFu + ((v.u >> 16) & 1u)) >> 16);
}
__device__ __forceinline__ float bf2f(u16 h) {
  union { unsigned u; float f; } v; v.u = ((unsigned)h) << 16; return v.f;
}

// async 16B global -> LDS (wave-uniform LDS base; HW writes base + lane*16)
__device__ __forceinline__ void gld_lds16(const u16* g, u16* l) {
  uint32_t lo = (uint32_t)(uintptr_t)l;
  lo = __builtin_amdgcn_readfirstlane(lo);
  auto* lp = (__attribute__((address_space(3))) uint32_t*)(uintptr_t)lo;
  auto* gp = (const __attribute__((address_space(1))) uint32_t*)(uintptr_t)g;
  __builtin_amdgcn_global_load_lds(gp, lp, 16, 0, 0);
}

// ---------------- weight fp32 -> bf16 ----------------
__global__ __launch_bounds__(256) void cvt_weights(
    const float* __restrict__ wq, const float* __restrict__ wp,
    u16* __restrict__ oq, u16* __restrict__ op) {
  int i = blockIdx.x * 256 + threadIdx.x;
  if (i < 1536 * 512) oq[i] = f2bf(wq[i]);
  if (i < 512 * 512)  op[i] = f2bf(wp[i]);
}

// ---------------- group norm stats ----------------
__global__ __launch_bounds__(256) void gn_stats(const float* __restrict__ x,
                                                float* __restrict__ stats) {
  int bg = blockIdx.x;  // 0..127
  const float* p = x + (size_t)bg * 65536;
  float s = 0.f, sq = 0.f;
  for (int i = threadIdx.x * 4; i < 65536; i += 1024) {
    float4 v = *(const float4*)(p + i);
    s += v.x + v.y + v.z + v.w;
    sq += v.x * v.x + v.y * v.y + v.z * v.z + v.w * v.w;
  }
  int lane = threadIdx.x & 63, w = threadIdx.x >> 6;
  for (int off = 32; off; off >>= 1) {
    s += __shfl_down(s, off);
    sq += __shfl_down(sq, off);
  }
  __shared__ float ls[4], lq[4];
  if (lane == 0) { ls[w] = s; lq[w] = sq; }
  __syncthreads();
  if (threadIdx.x == 0) {
    float S = ls[0] + ls[1] + ls[2] + ls[3];
    float Q = lq[0] + lq[1] + lq[2] + lq[3];
    float mean = S * (1.f / 65536.f);
    float var = Q * (1.f / 65536.f) - mean * mean;
    stats[bg * 2] = mean;
    stats[bg * 2 + 1] = rsqrtf(var + 1e-6f);
  }
}

// ---------------- group norm + transpose: x[b][c][n] -> xnT[b][n][c] bf16 ----
__global__ __launch_bounds__(256) void gn_norm_t(const float* __restrict__ x,
    const float* __restrict__ stats, const float* __restrict__ gamma,
    const float* __restrict__ beta, u16* __restrict__ xnT) {
  __shared__ u16 tile[64][72];
  int b = blockIdx.z;
  int c0 = blockIdx.y * 64, n0 = blockIdx.x * 64;
  int t = threadIdx.x;
  int cl = t >> 2, ng = (t & 3) * 16;
  int c = c0 + cl;
  float mean = stats[(b * 32 + (c >> 4)) * 2];
  float rstd = stats[(b * 32 + (c >> 4)) * 2 + 1];
  float a = gamma[c] * rstd;
  float b2 = beta[c] - mean * a;
  const float* src = x + ((size_t)b * 512 + c) * 4096 + n0 + ng;
  u16 e[16];
  #pragma unroll
  for (int q = 0; q < 4; ++q) {
    float4 v = *(const float4*)(src + q * 4);
    e[q * 4 + 0] = f2bf(v.x * a + b2);
    e[q * 4 + 1] = f2bf(v.y * a + b2);
    e[q * 4 + 2] = f2bf(v.z * a + b2);
    e[q * 4 + 3] = f2bf(v.w * a + b2);
  }
  #pragma unroll
  for (int j = 0; j < 16; ++j) tile[ng + j][cl] = e[j];
  __syncthreads();
  int nl = t >> 2, cg = (t & 3) * 16;
  uint4 w0 = *(const uint4*)&tile[nl][cg];
  uint4 w1 = *(const uint4*)&tile[nl][cg + 8];
  u16* dst = xnT + ((size_t)b * 4096 + n0 + nl) * 512 + c0 + cg;
  *(uint4*)dst = w0;
  *(uint4*)(dst + 8) = w1;
}

// ---------------- unified NT GEMM: C[m][n] = sum_k A[m*lda+k]*B[n*ldb+k] ----
// 128x128 tile, BK=64 (two 32-wide LDS panels), global_load_lds, 4 waves.
// bf16 EPIs use an LDS-bounce epilogue (coalesced dwordx4 stores).
// EPI: 2 = bf16 out plain (PV partial)
//      3 = fp32 out + bias[m] + resid (proj; direct epilogue)
//      4 = bf16 out, (acc+bias[n])*scale  (qk: m=spatial, n=channel)
//      5 = bf16 out, acc+bias[m]          (v:  m=channel, n=spatial)
//      7 = bf16 out exp(acc), atomicAdd row-sums into outF[m]
template<int EPI>
__global__ __launch_bounds__(256) void gemm_nt(
    const u16* __restrict__ A, const u16* __restrict__ B,
    int lda, int ldb, int K,
    const float* __restrict__ bias, const float* __restrict__ resid,
    float scale, float* __restrict__ outF, u16* __restrict__ outB, int ldo,
    size_t azs, size_t bzs, size_t ozs) {
  // staging: A panels [2][128][32] at 0, B panels at 8192; bounce: 128x136
  __shared__ __align__(16) u16 smem[17408];
  const size_t z = blockIdx.z;
  A += z * azs; B += z * bzs;
  const int t = threadIdx.x;
  const int wave = t >> 6, lane = t & 63;
  const int wm = wave >> 1, wn = wave & 1;
  const int quad = lane >> 4, li = lane & 15;
  const int m0 = blockIdx.y * 128, n0 = blockIdx.x * 128;

  const int srow = lane >> 2;
  const int scol = (lane & 3) * 8;
  const u16* gA[2];
  const u16* gB[2];
  u16* lA[2];
  u16* lB[2];
  #pragma unroll
  for (int r = 0; r < 2; ++r) {
    int rb = wave + 4 * r;
    gA[r] = A + (size_t)(m0 + rb * 16 + srow) * lda + scol;
    gB[r] = B + (size_t)(n0 + rb * 16 + srow) * ldb + scol;
    lA[r] = &smem[rb * 512];
    lB[r] = &smem[8192 + rb * 512];
  }

  f32x4 zero = {0.f, 0.f, 0.f, 0.f};
  f32x4 acc[4][4];
  #pragma unroll
  for (int i = 0; i < 4; ++i)
    #pragma unroll
    for (int j = 0; j < 4; ++j) acc[i][j] = zero;

  for (int kt = 0; kt < K; kt += 64) {
    __syncthreads();
    #pragma unroll
    for (int h = 0; h < 2; ++h)
      #pragma unroll
      for (int r = 0; r < 2; ++r) {
        gld_lds16(gA[r] + kt + 32 * h, lA[r] + h * 4096);
        gld_lds16(gB[r] + kt + 32 * h, lB[r] + h * 4096);
      }
    __syncthreads();
    #pragma unroll
    for (int h = 0; h < 2; ++h) {
      bf16x8 af[4], bf[4];
      #pragma unroll
      for (int i = 0; i < 4; ++i) {
        af[i] = *(const bf16x8*)&smem[h * 4096 +
                 (wm * 64 + i * 16 + li) * 32 + quad * 8];
        bf[i] = *(const bf16x8*)&smem[8192 + h * 4096 +
                 (wn * 64 + i * 16 + li) * 32 + quad * 8];
      }
      #pragma unroll
      for (int i = 0; i < 4; ++i)
        #pragma unroll
        for (int j = 0; j < 4; ++j)
          acc[i][j] = __builtin_amdgcn_mfma_f32_16x16x32_bf16(
              af[i], bf[j], acc[i][j], 0, 0, 0);
    }
  }

  if (EPI == 3) {
    // direct fp32 epilogue
    outF += z * ozs; resid += z * ozs;
    #pragma unroll
    for (int i = 0; i < 4; ++i)
      #pragma unroll
      for (int j = 0; j < 4; ++j) {
        int mB = m0 + wm * 64 + i * 16 + quad * 4;
        int n = n0 + wn * 64 + j * 16 + li;
        #pragma unroll
        for (int r = 0; r < 4; ++r) {
          int m = mB + r;
          float v = acc[i][j][r] + bias[m] + resid[(size_t)m * ldo + n];
          outF[(size_t)m * ldo + n] = v;
        }
      }
    return;
  }

  // bf16 epilogues: compute values, bounce through LDS, coalesced stores
  outB += z * ozs;
  __syncthreads();  // all waves done reading K-loop LDS
  #pragma unroll
  for (int i = 0; i < 4; ++i) {
    float rs[4] = {0.f, 0.f, 0.f, 0.f};
    #pragma unroll
    for (int j = 0; j < 4; ++j) {
      int lm = wm * 64 + i * 16 + quad * 4;
      int ln = wn * 64 + j * 16 + li;
      #pragma unroll
      for (int r = 0; r < 4; ++r) {
        float v = acc[i][j][r];
        u16 o;
        if (EPI == 2) {
          o = f2bf(v);
        } else if (EPI == 4) {
          o = f2bf((v + bias[n0 + ln]) * scale);
        } else if (EPI == 5) {
          o = f2bf(v + bias[m0 + lm + r]);
        } else {  // EPI 7
          float e = __expf(v);
          o = f2bf(e);
          rs[r] += e;
        }
        smem[(lm + r) * 136 + ln] = o;
      }
    }
    if (EPI == 7) {
      #pragma unroll
      for (int r = 0; r < 4; ++r) {
        rs[r] += __shfl_xor(rs[r], 1);
        rs[r] += __shfl_xor(rs[r], 2);
        rs[r] += __shfl_xor(rs[r], 4);
        rs[r] += __shfl_xor(rs[r], 8);
      }
      if (li == 0) {
        int mB = m0 + wm * 64 + i * 16 + quad * 4;
        #pragma unroll
        for (int r = 0; r < 4; ++r) atomicAdd(&outF[mB + r], rs[r]);
      }
    }
  }
  __syncthreads();
  {
    int row = t >> 1, half = t & 1;
    const u16* src = &smem[row * 136 + half * 64];
    u16* dst = outB + (size_t)(m0 + row) * ldo + n0 + half * 64;
    #pragma unroll
    for (int cc = 0; cc < 8; ++cc)
      *(uint4*)(dst + cc * 8) = *(const uint4*)(src + cc * 8);
  }
}

// -------- PV split-K reduce: ao = bf16((sum_z part[z]) / rowsum) ----------
__global__ __launch_bounds__(256) void pv_reduce(const u16* __restrict__ part,
    const float* __restrict__ rowsum, u16* __restrict__ ao) {
  size_t i = ((size_t)blockIdx.x * 256 + threadIdx.x) * 4;
  int row = (int)(i >> 9);
  float inv = __builtin_amdgcn_rcpf(rowsum[row]);
  float s0 = 0.f, s1 = 0.f, s2 = 0.f, s3 = 0.f;
  #pragma unroll
  for (int zz = 0; zz < 4; ++zz) {
    ushort4 p = *(const ushort4*)(part + (size_t)zz * 2097152 + i);
    s0 += bf2f(p.x); s1 += bf2f(p.y); s2 += bf2f(p.z); s3 += bf2f(p.w);
  }
  ushort4 o;
  o.x = f2bf(s0 * inv); o.y = f2bf(s1 * inv);
  o.z = f2bf(s2 * inv); o.w = f2bf(s3 * inv);
  *(ushort4*)(ao + i) = o;
}

extern "C" void kernel_launch(void* const* d_in, const int* in_sizes, int n_in,
                              void* d_out, int out_size, void* d_ws, size_t ws_size,
                              hipStream_t stream) {
  (void)in_sizes; (void)n_in; (void)out_size; (void)ws_size;
  const float* x      = (const float*)d_in[0];
  const float* gamma  = (const float*)d_in[1];
  const float* beta   = (const float*)d_in[2];
  const float* w_qkv  = (const float*)d_in[3];
  const float* b_qkv  = (const float*)d_in[4];
  const float* w_proj = (const float*)d_in[5];
  const float* b_proj = (const float*)d_in[6];
  float* out = (float*)d_out;

  const int C = 512, N = 4096;
  const size_t NC = (size_t)N * C;
  const float scale = 0.21022410381342863f;  // 512^-0.25

  char* ws = (char*)d_ws;
  size_t off = 0;
  auto alloc = [&](size_t bytes) -> char* {
    char* p = ws + off; off += (bytes + 255) & ~(size_t)255; return p;
  };
  u16*   wq_bf  = (u16*)alloc((size_t)1536 * 512 * 2);
  u16*   wp_bf  = (u16*)alloc((size_t)512 * 512 * 2);
  float* stats  = (float*)alloc(128 * 2 * 4);
  float* rowsum = (float*)alloc((size_t)4 * N * 4);
  u16*   xnT    = (u16*)alloc((size_t)4 * NC * 2);        // [b][n][c]
  u16*   qkT    = (u16*)alloc((size_t)4 * N * 1024 * 2);  // [b][i][o], o<1024
  u16*   vbf    = (u16*)alloc((size_t)4 * NC * 2);        // [b][c][j]
  u16*   ao     = (u16*)alloc((size_t)4 * NC * 2);        // [b][i][c]
  u16*   E      = (u16*)alloc((size_t)N * N * 2);         // per-batch exp(S)
  u16*   pvpart = (u16*)alloc((size_t)4 * NC * 2);        // per-batch [z][i][c]

  cvt_weights<<<3072, 256, 0, stream>>>(w_qkv, w_proj, wq_bf, wp_bf);
  gn_stats<<<128, 256, 0, stream>>>(x, stats);
  gn_norm_t<<<dim3(64, 8, 4), 256, 0, stream>>>(x, stats, gamma, beta, xnT);
  hipMemsetAsync(rowsum, 0, (size_t)4 * N * 4, stream);

  // qkT[b][i][o] = (sum_c xnT[b][i][c]*wq[o][c] + b_qkv[o]) * scale
  gemm_nt<4><<<dim3(8, 32, 4), 256, 0, stream>>>(
      xnT, wq_bf, 512, 512, 512, b_qkv, nullptr, scale,
      nullptr, qkT, 1024, NC, 0, (size_t)N * 1024);
  // vbf[b][c][j] = sum_k wq[1024+c][k]*xnT[b][j][k] + b_qkv[1024+c]
  gemm_nt<5><<<dim3(32, 4, 4), 256, 0, stream>>>(
      wq_bf + (size_t)1024 * 512, xnT, 512, 512, 512, b_qkv + 1024, nullptr,
      0.f, nullptr, vbf, 4096, 0, NC, NC);

  for (int b = 0; b < 4; ++b) {
    const u16* qkb = qkT + (size_t)b * N * 1024;
    // E[i][j] = bf16(exp(S[i][j])), rowsum[b][i] += partials
    gemm_nt<7><<<dim3(32, 32), 256, 0, stream>>>(
        qkb, qkb + 512, 1024, 1024, 512, nullptr, nullptr, 0.f,
        rowsum + (size_t)b * N, E, 4096, 0, 0, 0);
    // pvpart[z][i][c] = sum_{j in seg z} E[i][j]*v[c][j]   (bf16)
    gemm_nt<2><<<dim3(4, 32, 4), 256, 0, stream>>>(
        E, vbf + (size_t)b * NC, 4096, 4096, 1024, nullptr, nullptr, 0.f,
        nullptr, pvpart, 512, 1024, 1024, NC);
    // ao[b][i][c] = bf16(sum_z pvpart / rowsum[b][i])
    pv_reduce<<<2048, 256, 0, stream>>>(pvpart, rowsum + (size_t)b * N,
                                        ao + (size_t)b * NC);
  }

  // out[b][o][n] = sum_c wp[o][c]*ao[b][n][c] + b_proj[o] + x[b][o][n]
  gemm_nt<3><<<dim3(32, 4, 4), 256, 0, stream>>>(
      wp_bf, ao, 512, 512, 512, b_proj, x, 0.f,
      out, nullptr, 4096, 0, NC, NC);
}